// Round 2
// baseline (4018.937 us; speedup 1.0000x reference)
//
#include <hip/hip_runtime.h>
#include <math.h>

#define NN 50000
#define EE 400000
#define RR 3
#define NH 3
#define FIN 128
#define HID 64
#define FOUT 64
#define NC 16
#define NB 8

__device__ __forceinline__ void atomicMaxF(float* addr, float val) {
  int old = __float_as_int(*addr);
  while (__int_as_float(old) < val) {
    int assumed = old;
    old = atomicCAS((int*)addr, assumed, __float_as_int(val));
    if (old == assumed) break;
  }
}

// ---- degrees ----
__global__ void k_deg(const int* __restrict__ src, const int* __restrict__ dst,
                      int* __restrict__ degs, int* __restrict__ degd) {
  int i = blockIdx.x * 256 + threadIdx.x;
  if (i >= RR * EE) return;
  int r = i / EE;
  atomicAdd(&degs[r * NN + src[i]], 1);
  atomicAdd(&degd[r * NN + dst[i]], 1);
}

__global__ void k_norm(const int* __restrict__ degs, const int* __restrict__ degd,
                       float* __restrict__ ns, float* __restrict__ nd) {
  int i = blockIdx.x * 256 + threadIdx.x;
  if (i >= RR * NN) return;
  ns[i] = 1.0f / sqrtf((float)(degs[i] > 1 ? degs[i] : 1));
  nd[i] = 1.0f / sqrtf((float)(degd[i] > 1 ? degd[i] : 1));
}

// ---- conv1 matmul: hw[(r*NN+n)*HID+k] = ns[r][n] * sum_t x[n][t]*W1[r][t][k]
__global__ void k_mm1(const float* __restrict__ x, const float* __restrict__ W1,
                      const float* __restrict__ ns, float* __restrict__ hw) {
  int i = blockIdx.x * 256 + threadIdx.x;
  if (i >= RR * NN * HID) return;
  int k = i & (HID - 1);
  int n = (i / HID) % NN;
  int r = i / (NN * HID);
  const float* xr = x + (size_t)n * FIN;
  const float* w = W1 + (size_t)r * FIN * HID + k;
  float acc = 0.f;
#pragma unroll 8
  for (int t = 0; t < FIN; ++t) acc += xr[t] * w[t * HID];
  hw[i] = acc * ns[r * NN + n];
}

__global__ void k_scatter1(const int* __restrict__ src, const int* __restrict__ dst,
                           const float* __restrict__ hw, const float* __restrict__ nd,
                           float* __restrict__ h1) {
  int i = blockIdx.x * 256 + threadIdx.x;
  if (i >= RR * EE * HID) return;
  int k = i & (HID - 1);
  int e = (i / HID) % EE;
  int r = i / (EE * HID);
  int s = src[r * EE + e], d = dst[r * EE + e];
  atomicAdd(&h1[d * HID + k], hw[((size_t)r * NN + s) * HID + k] * nd[r * NN + d]);
}

// ---- add bias-sum + L2 normalize (one wave per node) ----
__global__ void k_normh1(float* __restrict__ h1, const float* __restrict__ b1) {
  int node = blockIdx.x * 4 + (threadIdx.x >> 6);
  int lane = threadIdx.x & 63;
  if (node >= NN) return;
  float v = h1[node * HID + lane] + b1[lane] + b1[HID + lane] + b1[2 * HID + lane];
  float s = v * v;
  for (int off = 32; off; off >>= 1) s += __shfl_xor(s, off);
  float nrm = sqrtf(s);
  nrm = nrm > 1e-12f ? nrm : 1e-12f;
  h1[node * HID + lane] = v / nrm;
}

// ---- GAT matmul: f[n][j] = sum_k h1[n][k]*Wg[r][k][j], j in [0,192)
__global__ void k_mmg(const float* __restrict__ h1, const float* __restrict__ Wg,
                      float* __restrict__ f, int r) {
  int i = blockIdx.x * 256 + threadIdx.x;
  if (i >= NN * NH * HID) return;
  int j = i % (NH * HID);
  int n = i / (NH * HID);
  const float* hr = h1 + n * HID;
  const float* w = Wg + (size_t)r * HID * NH * HID + j;
  float acc = 0.f;
#pragma unroll 8
  for (int t = 0; t < HID; ++t) acc += hr[t] * w[t * NH * HID];
  f[i] = acc;
}

__global__ void k_eler(const float* __restrict__ f, const float* __restrict__ al,
                       const float* __restrict__ ar, float* __restrict__ el,
                       float* __restrict__ er, int r) {
  int i = blockIdx.x * 256 + threadIdx.x;
  if (i >= NN * NH) return;
  int h = i % NH;
  int n = i / NH;
  const float* fr = f + (size_t)n * (NH * HID) + h * HID;
  const float* alr = al + r * NH * HID + h * HID;
  const float* arr = ar + r * NH * HID + h * HID;
  float a = 0.f, b = 0.f;
#pragma unroll 8
  for (int k = 0; k < HID; ++k) { a += fr[k] * alr[k]; b += fr[k] * arr[k]; }
  el[i] = a;
  er[i] = b;
}

__global__ void k_fillmz(float* __restrict__ m, float* __restrict__ z) {
  int i = blockIdx.x * 256 + threadIdx.x;
  if (i >= NN * NH) return;
  m[i] = -1e30f;
  z[i] = 0.f;
}

__global__ void k_emax(const int* __restrict__ src, const int* __restrict__ dst,
                       const float* __restrict__ el, const float* __restrict__ er,
                       float* __restrict__ m, int r) {
  int i = blockIdx.x * 256 + threadIdx.x;
  if (i >= EE * NH) return;
  int h = i % NH;
  int e = i / NH;
  int s = src[r * EE + e], d = dst[r * EE + e];
  float ev = el[s * NH + h] + er[d * NH + h];
  ev = ev > 0.f ? ev : 0.2f * ev;
  atomicMaxF(&m[d * NH + h], ev);
}

__global__ void k_eexp(const int* __restrict__ src, const int* __restrict__ dst,
                       const float* __restrict__ el, const float* __restrict__ er,
                       const float* __restrict__ m, float* __restrict__ albuf,
                       float* __restrict__ z, int r) {
  int i = blockIdx.x * 256 + threadIdx.x;
  if (i >= EE * NH) return;
  int h = i % NH;
  int e = i / NH;
  int s = src[r * EE + e], d = dst[r * EE + e];
  float ev = el[s * NH + h] + er[d * NH + h];
  ev = ev > 0.f ? ev : 0.2f * ev;
  float ez = __expf(ev - m[d * NH + h]);
  albuf[i] = ez;
  atomicAdd(&z[d * NH + h], ez);
}

__global__ void k_gatscat(const int* __restrict__ src, const int* __restrict__ dst,
                          const float* __restrict__ f, const float* __restrict__ albuf,
                          const float* __restrict__ z, float* __restrict__ gat, int r) {
  int i = blockIdx.x * 256 + threadIdx.x;
  if (i >= EE * HID) return;
  int k = i & (HID - 1);
  int e = i / HID;
  int s = src[r * EE + e], d = dst[r * EE + e];
#pragma unroll
  for (int h = 0; h < NH; ++h) {
    float a = albuf[e * NH + h] / (z[d * NH + h] + 1e-9f);
    atomicAdd(&gat[(size_t)d * (NH * HID) + h * HID + k],
              a * f[(size_t)s * (NH * HID) + h * HID + k]);
  }
}

__global__ void k_relubg(float* __restrict__ gat, const float* __restrict__ bg) {
  int i = blockIdx.x * 256 + threadIdx.x;
  if (i >= NN * NH * HID) return;
  int j = i % (NH * HID);
  float v = gat[i] + bg[j] + bg[NH * HID + j] + bg[2 * NH * HID + j];
  gat[i] = v > 0.f ? v : 0.f;
}

// ---- conv2 matmul: hw[n][h*64+o] = ns[r][n] * sum_k h2[n][h*64+k]*W2[r][k][o]
__global__ void k_mm2(const float* __restrict__ h2, const float* __restrict__ W2,
                      const float* __restrict__ ns, float* __restrict__ hw, int r) {
  int i = blockIdx.x * 256 + threadIdx.x;
  if (i >= NN * NH * FOUT) return;
  int o = i & (FOUT - 1);
  int j = i % (NH * FOUT);
  int h = j / FOUT;
  int n = i / (NH * FOUT);
  const float* hr = h2 + (size_t)n * (NH * HID) + h * HID;
  const float* w = W2 + (size_t)r * HID * FOUT + o;
  float acc = 0.f;
#pragma unroll 8
  for (int t = 0; t < HID; ++t) acc += hr[t] * w[t * FOUT];
  hw[i] = acc * ns[r * NN + n];
}

__global__ void k_scat2(const int* __restrict__ src, const int* __restrict__ dst,
                        const float* __restrict__ hw, const float* __restrict__ nd,
                        float* __restrict__ agg2, int r) {
  int i = blockIdx.x * 256 + threadIdx.x;
  if (i >= EE * FOUT) return;
  int o = i & (FOUT - 1);
  int e = i / FOUT;
  int s = src[r * EE + e], d = dst[r * EE + e];
  float ndv = nd[r * NN + d];
#pragma unroll
  for (int h = 0; h < NH; ++h)
    atomicAdd(&agg2[(size_t)d * (NH * FOUT) + h * FOUT + o],
              hw[(size_t)s * (NH * FOUT) + h * FOUT + o] * ndv);
}

__global__ void k_sig(float* __restrict__ agg2, const float* __restrict__ b2) {
  int i = blockIdx.x * 256 + threadIdx.x;
  if (i >= NN * NH * FOUT) return;
  int o = i & (FOUT - 1);
  float v = agg2[i] + b2[o] + b2[FOUT + o] + b2[2 * FOUT + o];
  agg2[i] = 1.0f / (1.0f + __expf(-v));
}

__global__ void k_cnt(const int* __restrict__ gid, float* __restrict__ cnt) {
  int i = blockIdx.x * 256 + threadIdx.x;
  if (i >= NN) return;
  atomicAdd(&cnt[gid[i]], 1.0f);
}

__global__ void k_pool(const float* __restrict__ h3, const int* __restrict__ gid,
                       float* __restrict__ pooled) {
  int j = threadIdx.x;  // 0..191
  int start = blockIdx.x * 128;
  if (start >= NN) return;
  int end = start + 128;
  if (end > NN) end = NN;
  int gcur = gid[start];
  float acc = 0.f;
  for (int n = start; n < end; ++n) {
    int g = gid[n];
    if (g != gcur) {
      atomicAdd(&pooled[gcur * (NH * FOUT) + j], acc);
      acc = 0.f;
      gcur = g;
    }
    acc += h3[(size_t)n * (NH * FOUT) + j];
  }
  atomicAdd(&pooled[gcur * (NH * FOUT) + j], acc);
}

__global__ void k_final(const float* __restrict__ pooled, const float* __restrict__ cnt,
                        const float* __restrict__ Wc, const float* __restrict__ bc,
                        float* __restrict__ out) {
  int t = threadIdx.x;
  if (t >= NB * NH) return;
  int b = t / NH;
  float inv = 1.0f / fmaxf(cnt[b], 1.0f);
  const float* p = pooled + t * FOUT;
  float sacc = 0.f;
  for (int c = 0; c < NC; ++c) {
    float acc = bc[c];
    for (int o = 0; o < FOUT; ++o) acc += p[o] * inv * Wc[o * NC + c];
    sacc += 1.0f / (1.0f + __expf(-acc));
  }
  out[t] = sacc * (1.0f / NC);
}

extern "C" void kernel_launch(void* const* d_in, const int* in_sizes, int n_in,
                              void* d_out, int out_size, void* d_ws, size_t ws_size,
                              hipStream_t stream) {
  const float* x = (const float*)d_in[0];
  const int* src = (const int*)d_in[1];
  const int* dst = (const int*)d_in[2];
  const int* gid = (const int*)d_in[3];
  const float* W1 = (const float*)d_in[4];
  const float* b1 = (const float*)d_in[5];
  const float* Wg = (const float*)d_in[6];
  const float* al = (const float*)d_in[7];
  const float* ar = (const float*)d_in[8];
  const float* bg = (const float*)d_in[9];
  const float* W2 = (const float*)d_in[10];
  const float* b2 = (const float*)d_in[11];
  const float* Wc = (const float*)d_in[12];
  const float* bc = (const float*)d_in[13];
  float* out = (float*)d_out;

  // ---- workspace layout ----
  float* W = (float*)d_ws;
  // zero region (single memset)
  float* h1 = W;                                  // NN*HID
  float* gat = h1 + (size_t)NN * HID;             // NN*NH*HID
  float* agg2 = gat + (size_t)NN * NH * HID;      // NN*NH*FOUT
  float* pooled = agg2 + (size_t)NN * NH * FOUT;  // NB*NH*FOUT
  float* cnt = pooled + NB * NH * FOUT;           // NB
  int* degs = (int*)(cnt + NB);                   // RR*NN
  int* degd = degs + RR * NN;                     // RR*NN
  size_t zero_bytes = ((size_t)NN * HID + (size_t)NN * NH * HID + (size_t)NN * NH * FOUT +
                       NB * NH * FOUT + NB) * 4 + (size_t)2 * RR * NN * 4;
  // non-zero region
  float* A = (float*)(degd + RR * NN);  // max(RR*NN*HID, NN*192) = 9.6M floats
  float* ns = A + (size_t)NN * NH * HID;
  float* nd = ns + RR * NN;
  float* el = nd + RR * NN;
  float* er = el + NN * NH;
  float* m_ = er + NN * NH;
  float* z_ = m_ + NN * NH;
  float* albuf = z_ + NN * NH;  // EE*NH

  hipMemsetAsync(d_ws, 0, zero_bytes, stream);

  // degrees + norms
  k_deg<<<(RR * EE + 255) / 256, 256, 0, stream>>>(src, dst, degs, degd);
  k_norm<<<(RR * NN + 255) / 256, 256, 0, stream>>>(degs, degd, ns, nd);

  // conv1
  k_mm1<<<(RR * NN * HID + 255) / 256, 256, 0, stream>>>(x, W1, ns, A);
  k_scatter1<<<(RR * EE * HID + 255) / 256, 256, 0, stream>>>(src, dst, A, nd, h1);
  k_normh1<<<(NN + 3) / 4, 256, 0, stream>>>(h1, b1);

  // GAT (per relation)
  for (int r = 0; r < RR; ++r) {
    k_mmg<<<(NN * NH * HID + 255) / 256, 256, 0, stream>>>(h1, Wg, A, r);
    k_eler<<<(NN * NH + 255) / 256, 256, 0, stream>>>(A, al, ar, el, er, r);
    k_fillmz<<<(NN * NH + 255) / 256, 256, 0, stream>>>(m_, z_);
    k_emax<<<(EE * NH + 255) / 256, 256, 0, stream>>>(src, dst, el, er, m_, r);
    k_eexp<<<(EE * NH + 255) / 256, 256, 0, stream>>>(src, dst, el, er, m_, albuf, z_, r);
    k_gatscat<<<(EE * HID + 255) / 256, 256, 0, stream>>>(src, dst, A, albuf, z_, gat, r);
  }
  k_relubg<<<(NN * NH * HID + 255) / 256, 256, 0, stream>>>(gat, bg);

  // conv2 (per relation)
  for (int r = 0; r < RR; ++r) {
    k_mm2<<<(NN * NH * FOUT + 255) / 256, 256, 0, stream>>>(gat, W2, ns, A, r);
    k_scat2<<<(EE * FOUT + 255) / 256, 256, 0, stream>>>(src, dst, A, nd, agg2, r);
  }
  k_sig<<<(NN * NH * FOUT + 255) / 256, 256, 0, stream>>>(agg2, b2);

  // pooling + classifier
  k_cnt<<<(NN + 255) / 256, 256, 0, stream>>>(gid, cnt);
  k_pool<<<(NN + 127) / 128, 192, 0, stream>>>(agg2, gid, pooled);
  k_final<<<1, 64, 0, stream>>>(pooled, cnt, Wc, bc, out);
}

// Round 3
// 2112.604 us; speedup vs baseline: 1.9024x; 1.9024x over previous
//
#include <hip/hip_runtime.h>
#include <math.h>

#define NN 50000
#define EE 400000
#define RR 3
#define NH 3
#define FIN 128
#define HID 64
#define FOUT 64
#define NC 16
#define NB 8

// ======== degree histogram (int atomics, low contention) ========
__global__ void k_deg(const int* __restrict__ src, const int* __restrict__ dst,
                      int* __restrict__ degs, int* __restrict__ degd) {
  int i = blockIdx.x * 256 + threadIdx.x;
  if (i >= RR * EE) return;
  int r = i / EE;
  atomicAdd(&degs[r * NN + src[i]], 1);
  atomicAdd(&degd[r * NN + dst[i]], 1);
}

__global__ void k_norm(const int* __restrict__ degs, const int* __restrict__ degd,
                       float* __restrict__ ns, float* __restrict__ nd) {
  int i = blockIdx.x * 256 + threadIdx.x;
  if (i >= RR * NN) return;
  ns[i] = 1.0f / sqrtf((float)(degs[i] > 1 ? degs[i] : 1));
  nd[i] = 1.0f / sqrtf((float)(degd[i] > 1 ? degd[i] : 1));
}

// ======== exclusive scan over degd (RR*NN) -> offs, 3 kernels ========
__global__ void k_scan1(const int* __restrict__ deg, int* __restrict__ offs,
                        int* __restrict__ bsum) {
  __shared__ int sh[256];
  int gid = blockIdx.x * 256 + threadIdx.x;
  int v = (gid < RR * NN) ? deg[gid] : 0;
  sh[threadIdx.x] = v;
  __syncthreads();
  for (int off = 1; off < 256; off <<= 1) {
    int t = (threadIdx.x >= off) ? sh[threadIdx.x - off] : 0;
    __syncthreads();
    sh[threadIdx.x] += t;
    __syncthreads();
  }
  if (gid < RR * NN) offs[gid] = sh[threadIdx.x] - v;  // exclusive within block
  if (threadIdx.x == 255) bsum[blockIdx.x] = sh[255];
}

__global__ void k_scan2(int* __restrict__ bsum, int nb) {
  __shared__ int sh[1024];
  int v = (threadIdx.x < nb) ? bsum[threadIdx.x] : 0;
  sh[threadIdx.x] = v;
  __syncthreads();
  for (int off = 1; off < 1024; off <<= 1) {
    int t = (threadIdx.x >= off) ? sh[threadIdx.x - off] : 0;
    __syncthreads();
    sh[threadIdx.x] += t;
    __syncthreads();
  }
  if (threadIdx.x < nb) bsum[threadIdx.x] = sh[threadIdx.x] - v;  // exclusive
}

__global__ void k_scan3(int* __restrict__ offs, const int* __restrict__ bsum,
                        int* __restrict__ cursor) {
  int i = blockIdx.x * 256 + threadIdx.x;
  if (i >= RR * NN) return;
  int v = offs[i] + bsum[i / 256];
  offs[i] = v;
  cursor[i] = v;
}

// ======== bucket edges by destination: esrc[pos] = src ========
__global__ void k_fill(const int* __restrict__ src, const int* __restrict__ dst,
                       int* __restrict__ cursor, int* __restrict__ esrc) {
  int i = blockIdx.x * 256 + threadIdx.x;
  if (i >= RR * EE) return;
  int r = i / EE;
  int d = dst[i];
  int pos = atomicAdd(&cursor[r * NN + d], 1);
  esrc[pos] = src[i];
}

// ======== conv1 matmul: hw[(r*NN+n)*HID+k] = ns[r][n] * sum_t x[n][t]*W1[r][t][k]
__global__ void k_mm1(const float* __restrict__ x, const float* __restrict__ W1,
                      const float* __restrict__ ns, float* __restrict__ hw) {
  int i = blockIdx.x * 256 + threadIdx.x;
  if (i >= RR * NN * HID) return;
  int k = i & (HID - 1);
  int n = (i / HID) % NN;
  int r = i / (NN * HID);
  const float* xr = x + (size_t)n * FIN;
  const float* w = W1 + (size_t)r * FIN * HID + k;
  float acc = 0.f;
#pragma unroll 8
  for (int t = 0; t < FIN; ++t) acc += xr[t] * w[t * HID];
  hw[i] = acc * ns[r * NN + n];
}

// ======== conv1 gather + bias + L2 normalize (one wave per node) ========
__global__ void k_g1(const int* __restrict__ offs, const int* __restrict__ degd,
                     const int* __restrict__ esrc, const float* __restrict__ hw,
                     const float* __restrict__ nd, const float* __restrict__ b1,
                     float* __restrict__ h1) {
  int node = blockIdx.x * 4 + (threadIdx.x >> 6);
  int lane = threadIdx.x & 63;
  if (node >= NN) return;
  float v = 0.f;
#pragma unroll
  for (int r = 0; r < RR; ++r) {
    int start = offs[r * NN + node];
    int deg = degd[r * NN + node];
    float t = 0.f;
    for (int j = 0; j < deg; ++j) {
      int s = esrc[start + j];
      t += hw[((size_t)r * NN + s) * HID + lane];
    }
    v += t * nd[r * NN + node];
  }
  v += b1[lane] + b1[HID + lane] + b1[2 * HID + lane];
  float sq = v * v;
  for (int off = 32; off; off >>= 1) sq += __shfl_xor(sq, off);
  float nrm = sqrtf(sq);
  nrm = nrm > 1e-12f ? nrm : 1e-12f;
  h1[node * HID + lane] = v / nrm;
}

// ======== GAT matmul: f[n][j] = sum_k h1[n][k]*Wg[r][k][j], j in [0,192)
__global__ void k_mmg(const float* __restrict__ h1, const float* __restrict__ Wg,
                      float* __restrict__ f, int r) {
  int i = blockIdx.x * 256 + threadIdx.x;
  if (i >= NN * NH * HID) return;
  int j = i % (NH * HID);
  int n = i / (NH * HID);
  const float* hr = h1 + n * HID;
  const float* w = Wg + (size_t)r * HID * NH * HID + j;
  float acc = 0.f;
#pragma unroll 8
  for (int t = 0; t < HID; ++t) acc += hr[t] * w[t * NH * HID];
  f[i] = acc;
}

__global__ void k_eler(const float* __restrict__ f, const float* __restrict__ al,
                       const float* __restrict__ ar, float* __restrict__ el,
                       float* __restrict__ er, int r) {
  int i = blockIdx.x * 256 + threadIdx.x;
  if (i >= NN * NH) return;
  int h = i % NH;
  int n = i / NH;
  const float* fr = f + (size_t)n * (NH * HID) + h * HID;
  const float* alr = al + r * NH * HID + h * HID;
  const float* arr = ar + r * NH * HID + h * HID;
  float a = 0.f, b = 0.f;
#pragma unroll 8
  for (int k = 0; k < HID; ++k) { a += fr[k] * alr[k]; b += fr[k] * arr[k]; }
  el[i] = a;
  er[i] = b;
}

// ======== GAT gather: softmax over in-edges + weighted feature sum ========
__global__ void k_gatg(const int* __restrict__ offs, const int* __restrict__ degd,
                       const int* __restrict__ esrc, const float* __restrict__ f,
                       const float* __restrict__ el, const float* __restrict__ er,
                       float* __restrict__ gat, int r, int accf) {
  int node = blockIdx.x * 4 + (threadIdx.x >> 6);
  int lane = threadIdx.x & 63;
  if (node >= NN) return;
  int start = offs[r * NN + node];
  int deg = degd[r * NN + node];
  float erv[NH], m[NH];
#pragma unroll
  for (int h = 0; h < NH; ++h) {
    erv[h] = er[node * NH + h];
    m[h] = -1e30f;
  }
  // pass 1: max (wave-uniform scalar work, lane-redundant)
  for (int j = 0; j < deg; ++j) {
    int s = esrc[start + j];
#pragma unroll
    for (int h = 0; h < NH; ++h) {
      float ev = el[s * NH + h] + erv[h];
      ev = ev > 0.f ? ev : 0.2f * ev;
      m[h] = fmaxf(m[h], ev);
    }
  }
  // pass 2: accumulate z and unnormalized weighted features
  float z[NH] = {0.f, 0.f, 0.f};
  float acc[NH] = {0.f, 0.f, 0.f};
  for (int j = 0; j < deg; ++j) {
    int s = esrc[start + j];
#pragma unroll
    for (int h = 0; h < NH; ++h) {
      float ev = el[s * NH + h] + erv[h];
      ev = ev > 0.f ? ev : 0.2f * ev;
      float w = __expf(ev - m[h]);
      z[h] += w;
      acc[h] += w * f[(size_t)s * (NH * HID) + h * HID + lane];
    }
  }
#pragma unroll
  for (int h = 0; h < NH; ++h) {
    float outv = acc[h] / (z[h] + 1e-9f);
    size_t idx = (size_t)node * (NH * HID) + h * HID + lane;
    gat[idx] = (accf ? gat[idx] : 0.f) + outv;
  }
}

__global__ void k_relubg(float* __restrict__ gat, const float* __restrict__ bg) {
  int i = blockIdx.x * 256 + threadIdx.x;
  if (i >= NN * NH * HID) return;
  int j = i % (NH * HID);
  float v = gat[i] + bg[j] + bg[NH * HID + j] + bg[2 * NH * HID + j];
  gat[i] = v > 0.f ? v : 0.f;
}

// ======== conv2 matmul: hw[n][h*64+o] = ns[r][n]*sum_k gat[n][h*64+k]*W2[r][k][o]
__global__ void k_mm2(const float* __restrict__ h2, const float* __restrict__ W2,
                      const float* __restrict__ ns, float* __restrict__ hw, int r) {
  int i = blockIdx.x * 256 + threadIdx.x;
  if (i >= NN * NH * FOUT) return;
  int o = i & (FOUT - 1);
  int j = i % (NH * FOUT);
  int h = j / FOUT;
  int n = i / (NH * FOUT);
  const float* hr = h2 + (size_t)n * (NH * HID) + h * HID;
  const float* w = W2 + (size_t)r * HID * FOUT + o;
  float acc = 0.f;
#pragma unroll 8
  for (int t = 0; t < HID; ++t) acc += hr[t] * w[t * FOUT];
  hw[i] = acc * ns[r * NN + n];
}

// ======== conv2 gather ========
__global__ void k_g2(const int* __restrict__ offs, const int* __restrict__ degd,
                     const int* __restrict__ esrc, const float* __restrict__ hw,
                     const float* __restrict__ nd, float* __restrict__ agg2,
                     int r, int accf) {
  int node = blockIdx.x * 4 + (threadIdx.x >> 6);
  int lane = threadIdx.x & 63;
  if (node >= NN) return;
  int start = offs[r * NN + node];
  int deg = degd[r * NN + node];
  float acc[NH] = {0.f, 0.f, 0.f};
  for (int j = 0; j < deg; ++j) {
    int s = esrc[start + j];
#pragma unroll
    for (int h = 0; h < NH; ++h)
      acc[h] += hw[(size_t)s * (NH * FOUT) + h * FOUT + lane];
  }
  float ndv = nd[r * NN + node];
#pragma unroll
  for (int h = 0; h < NH; ++h) {
    size_t idx = (size_t)node * (NH * FOUT) + h * FOUT + lane;
    agg2[idx] = (accf ? agg2[idx] : 0.f) + acc[h] * ndv;
  }
}

__global__ void k_sig(float* __restrict__ agg2, const float* __restrict__ b2) {
  int i = blockIdx.x * 256 + threadIdx.x;
  if (i >= NN * NH * FOUT) return;
  int o = i & (FOUT - 1);
  float v = agg2[i] + b2[o] + b2[FOUT + o] + b2[2 * FOUT + o];
  agg2[i] = 1.0f / (1.0f + __expf(-v));
}

// ======== graph-size counts (LDS-reduced) ========
__global__ void k_cnt2(const int* __restrict__ gid, float* __restrict__ cnt) {
  __shared__ int loc[NB];
  if (threadIdx.x < NB) loc[threadIdx.x] = 0;
  __syncthreads();
  int i = blockIdx.x * 256 + threadIdx.x;
  if (i < NN) atomicAdd(&loc[gid[i]], 1);
  __syncthreads();
  if (threadIdx.x < NB) atomicAdd(&cnt[threadIdx.x], (float)loc[threadIdx.x]);
}

__global__ void k_pool(const float* __restrict__ h3, const int* __restrict__ gid,
                       float* __restrict__ pooled) {
  int j = threadIdx.x;  // 0..191
  int start = blockIdx.x * 128;
  if (start >= NN) return;
  int end = start + 128;
  if (end > NN) end = NN;
  int gcur = gid[start];
  float acc = 0.f;
  for (int n = start; n < end; ++n) {
    int g = gid[n];
    if (g != gcur) {
      atomicAdd(&pooled[gcur * (NH * FOUT) + j], acc);
      acc = 0.f;
      gcur = g;
    }
    acc += h3[(size_t)n * (NH * FOUT) + j];
  }
  atomicAdd(&pooled[gcur * (NH * FOUT) + j], acc);
}

__global__ void k_final(const float* __restrict__ pooled, const float* __restrict__ cnt,
                        const float* __restrict__ Wc, const float* __restrict__ bc,
                        float* __restrict__ out) {
  int t = threadIdx.x;
  if (t >= NB * NH) return;
  int b = t / NH;
  float inv = 1.0f / fmaxf(cnt[b], 1.0f);
  const float* p = pooled + t * FOUT;
  float sacc = 0.f;
  for (int c = 0; c < NC; ++c) {
    float acc = bc[c];
    for (int o = 0; o < FOUT; ++o) acc += p[o] * inv * Wc[o * NC + c];
    sacc += 1.0f / (1.0f + __expf(-acc));
  }
  out[t] = sacc * (1.0f / NC);
}

extern "C" void kernel_launch(void* const* d_in, const int* in_sizes, int n_in,
                              void* d_out, int out_size, void* d_ws, size_t ws_size,
                              hipStream_t stream) {
  const float* x = (const float*)d_in[0];
  const int* src = (const int*)d_in[1];
  const int* dst = (const int*)d_in[2];
  const int* gid = (const int*)d_in[3];
  const float* W1 = (const float*)d_in[4];
  const float* b1 = (const float*)d_in[5];
  const float* Wg = (const float*)d_in[6];
  const float* al = (const float*)d_in[7];
  const float* ar = (const float*)d_in[8];
  const float* bg = (const float*)d_in[9];
  const float* W2 = (const float*)d_in[10];
  const float* b2 = (const float*)d_in[11];
  const float* Wc = (const float*)d_in[12];
  const float* bc = (const float*)d_in[13];
  float* out = (float*)d_out;

  // ---- workspace layout ----
  // zero region: degs, degd (histograms), cnt, pooled (atomic accumulators)
  int* degs = (int*)d_ws;                        // RR*NN
  int* degd = degs + RR * NN;                    // RR*NN
  float* cnt = (float*)(degd + RR * NN);         // NB
  float* pooled = cnt + NB;                      // NB*NH*FOUT
  size_t zero_bytes = ((size_t)2 * RR * NN + NB + NB * NH * FOUT) * 4;
  // non-zero region (fully written before read)
  int* offs = (int*)(pooled + NB * NH * FOUT);   // RR*NN (+1 pad)
  int* cursor = offs + RR * NN + 1;              // RR*NN
  int* bsum = cursor + RR * NN;                  // 1024
  int* esrc = bsum + 1024;                       // RR*EE (bucketed by dst)
  float* ns = (float*)(esrc + (size_t)RR * EE);  // RR*NN
  float* nd = ns + RR * NN;                      // RR*NN
  float* el = nd + RR * NN;                      // NN*NH
  float* er = el + NN * NH;                      // NN*NH
  float* h1 = er + NN * NH;                      // NN*HID
  float* gat = h1 + (size_t)NN * HID;            // NN*NH*HID
  float* agg2 = gat + (size_t)NN * NH * HID;     // NN*NH*FOUT
  float* A = agg2 + (size_t)NN * NH * FOUT;      // RR*NN*HID == NN*192 staging

  hipMemsetAsync(d_ws, 0, zero_bytes, stream);

  const int nscan = RR * NN;
  const int nblk1 = (nscan + 255) / 256;  // 586 <= 1024

  // degrees + norms + CSR build
  k_deg<<<(RR * EE + 255) / 256, 256, 0, stream>>>(src, dst, degs, degd);
  k_norm<<<(nscan + 255) / 256, 256, 0, stream>>>(degs, degd, ns, nd);
  k_scan1<<<nblk1, 256, 0, stream>>>(degd, offs, bsum);
  k_scan2<<<1, 1024, 0, stream>>>(bsum, nblk1);
  k_scan3<<<nblk1, 256, 0, stream>>>(offs, bsum, cursor);
  k_fill<<<(RR * EE + 255) / 256, 256, 0, stream>>>(src, dst, cursor, esrc);

  // conv1: matmul (all relations) + gather + bias + L2-normalize
  k_mm1<<<(RR * NN * HID + 255) / 256, 256, 0, stream>>>(x, W1, ns, A);
  k_g1<<<(NN + 3) / 4, 256, 0, stream>>>(offs, degd, esrc, A, nd, b1, h1);

  // GAT per relation (gather-based edge softmax)
  for (int r = 0; r < RR; ++r) {
    k_mmg<<<(NN * NH * HID + 255) / 256, 256, 0, stream>>>(h1, Wg, A, r);
    k_eler<<<(NN * NH + 255) / 256, 256, 0, stream>>>(A, al, ar, el, er, r);
    k_gatg<<<(NN + 3) / 4, 256, 0, stream>>>(offs, degd, esrc, A, el, er, gat, r, r != 0);
  }
  k_relubg<<<(NN * NH * HID + 255) / 256, 256, 0, stream>>>(gat, bg);

  // conv2 per relation (gather-based)
  for (int r = 0; r < RR; ++r) {
    k_mm2<<<(NN * NH * FOUT + 255) / 256, 256, 0, stream>>>(gat, W2, ns, A, r);
    k_g2<<<(NN + 3) / 4, 256, 0, stream>>>(offs, degd, esrc, A, nd, agg2, r, r != 0);
  }
  k_sig<<<(NN * NH * FOUT + 255) / 256, 256, 0, stream>>>(agg2, b2);

  // pooling + classifier
  k_cnt2<<<(NN + 255) / 256, 256, 0, stream>>>(gid, cnt);
  k_pool<<<(NN + 127) / 128, 192, 0, stream>>>(agg2, gid, pooled);
  k_final<<<1, 64, 0, stream>>>(pooled, cnt, Wc, bc, out);
}